// Round 1
// baseline (96.093 us; speedup 1.0000x reference)
//
#include <hip/hip_runtime.h>
#include <math.h>

#define N 1024
#define B 32
#define JC 8           // j-chunks per row
#define CHUNK (N / JC) // 128
#define SIGMA 1.0f
#define FEPS 1.1920928955078125e-07f   // np.finfo(float32).eps
#define LOG2E 1.4426950408889634f

#if defined(__has_builtin) && __has_builtin(__builtin_amdgcn_exp2f)
#define EXP2F(x) __builtin_amdgcn_exp2f(x)
#else
#define EXP2F(x) exp2f(x)
#endif

// K1: zero d_out + partial rank counts over j-chunks.
// grid = B*JC blocks of 256 threads. block bx -> row r = bx>>3, chunk jc = bx&7.
// rank_part layout: [jc][r][i]
__global__ __launch_bounds__(256) void k1_rank(const float* __restrict__ a,
                                               float* __restrict__ out,
                                               int* __restrict__ rank_part) {
    const int bx = blockIdx.x;
    const int r = bx >> 3, jc = bx & 7;
    const int tid = threadIdx.x;

    // zero d_out (32769 floats across 65536 threads); later kernels atomicAdd
    const int gid = bx * 256 + tid;
    if (gid < B * N + 1) out[gid] = 0.0f;

    __shared__ float sA[CHUNK];
    if (tid < CHUNK) sA[tid] = a[r * N + jc * CHUNK + tid];

    float ai[4];
    int ig[4];
#pragma unroll
    for (int k = 0; k < 4; k++) {
        ig[k] = tid + k * 256;
        ai[k] = a[r * N + ig[k]];
    }
    __syncthreads();

    int cnt[4] = {0, 0, 0, 0};
    for (int j = 0; j < CHUNK; j++) {
        const float aj = sA[j];
        const int jg = jc * CHUNK + j;
#pragma unroll
        for (int k = 0; k < 4; k++) {
            // stable descending rank: count (a_j > a_i) or (tie and j < i)
            cnt[k] += (aj > ai[k]) ? 1 : ((aj == ai[k] && jg < ig[k]) ? 1 : 0);
        }
    }
#pragma unroll
    for (int k = 0; k < 4; k++)
        rank_part[(jc * B + r) * N + ig[k]] = cnt[k];
}

// K2: reduce rank partials -> pi -> ilr; histogram-based idcg; pack per-element
// float4 (p2y*2sigma/(idcg+eps), ilr, a*log2e, 0); atomicAdd row-sum(a) to loss.
// grid = B blocks of 1024 threads.
__global__ __launch_bounds__(1024) void k2_prep(const float* __restrict__ a,
                                                const float* __restrict__ y,
                                                const int* __restrict__ rank_part,
                                                float4* __restrict__ data,
                                                float* __restrict__ out) {
    const int r = blockIdx.x, tid = threadIdx.x;
    const float ai = a[r * N + tid];
    const float yi = y[r * N + tid];

    int cnt = 0;
#pragma unroll
    for (int jc = 0; jc < JC; jc++) cnt += rank_part[(jc * B + r) * N + tid];
    const int pi = cnt + 1;                       // 1-indexed rank
    const float ilr = __builtin_amdgcn_rcpf(__log2f((float)(pi + 1)));

    // histogram of y (values 0..4) for idcg-by-counting
    __shared__ int h[5];
    if (tid < 5) h[tid] = 0;
    __syncthreads();
    atomicAdd(&h[(int)yi], 1);
    __syncthreads();

    const int p4 = h[4];
    const int p3 = p4 + h[3];
    const int p2 = p3 + h[2];
    const int p1 = p2 + h[1];
    const int v = (tid < p4) ? 4 : (tid < p3) ? 3 : (tid < p2) ? 2 : (tid < p1) ? 1 : 0;
    const float gain = (float)((1 << v) - 1);
    float term = gain * __builtin_amdgcn_rcpf(__log2f((float)(tid + 2)));

    // block-reduce idcg (term) and row-sum of a (for the placeholder loss)
    float t = term, s = ai;
#pragma unroll
    for (int off = 32; off >= 1; off >>= 1) {
        t += __shfl_down(t, off, 64);
        s += __shfl_down(s, off, 64);
    }
    __shared__ float wt[16], wsm[16];
    __shared__ float sC;
    const int wid = tid >> 6, lane = tid & 63;
    if (lane == 0) { wt[wid] = t; wsm[wid] = s; }
    __syncthreads();
    if (tid == 0) {
        float idcg = 0.f, asum = 0.f;
        for (int w = 0; w < 16; w++) { idcg += wt[w]; asum += wsm[w]; }
        sC = 2.0f * SIGMA / (idcg + FEPS);
        atomicAdd(out, asum);   // loss = sum(a)
    }
    __syncthreads();
    const float c = sC;
    const float p2ys = EXP2F(yi) * c;   // folds 2*sigma/(idcg+eps) into the gain
    const float sa = ai * LOG2E;        // pre-scale so inner loop uses exp2 directly
    data[r * N + tid] = make_float4(p2ys, ilr, sa, 0.f);
}

// K3: pairwise gradient. grid = B*JC blocks of 1024 threads.
// block bx -> row r = bx>>3, j-chunk jc = bx&7; thread owns i = tid, loops 128 j's
// from LDS (wave-uniform index -> broadcast, conflict-free). atomicAdd partials.
__global__ __launch_bounds__(1024) void k3_grad(const float4* __restrict__ data,
                                                float* __restrict__ out) {
    const int bx = blockIdx.x;
    const int r = bx >> 3, jc = bx & 7;
    const int tid = threadIdx.x;

    __shared__ float4 sj[CHUNK];
    if (tid < CHUNK) sj[tid] = data[r * N + jc * CHUNK + tid];
    const float4 di = data[r * N + tid];
    __syncthreads();

    float acc = 0.f;
#pragma unroll 4
    for (int j = 0; j < CHUNK; j++) {
        const float4 dj = sj[j];
        const float dg = di.x - dj.x;        // scaled gain diff; sign == sign(y_i - y_j)
        const float dl = di.y - dj.y;        // inv-logrank diff
        const float da = di.z - dj.z;        // (a_i - a_j) * log2(e)
        const float num = dg * fabsf(dl);    // = s * |delta_ndcg| * (idcg-scale folded)
        const float x = (dg >= 0.f) ? da : -da;  // s * da (dg==0 -> num==0, x harmless)
        const float e = EXP2F(x);            // exp(s*(a_i-a_j))
        const float rcp = __builtin_amdgcn_rcpf(1.0f + e);
        acc = fmaf(num, rcp, acc);
    }
    atomicAdd(&out[1 + r * N + tid], -acc);
}

extern "C" void kernel_launch(void* const* d_in, const int* in_sizes, int n_in,
                              void* d_out, int out_size, void* d_ws, size_t ws_size,
                              hipStream_t stream) {
    (void)in_sizes; (void)n_in; (void)out_size; (void)ws_size;
    const float* a = (const float*)d_in[0];
    const float* y = (const float*)d_in[1];
    float* out = (float*)d_out;

    int* rank_part = (int*)d_ws;                                   // 8*32*1024 ints = 1 MB
    float4* data = (float4*)((char*)d_ws + (size_t)JC * B * N * sizeof(int)); // 512 KB

    hipLaunchKernelGGL(k1_rank, dim3(B * JC), dim3(256), 0, stream, a, out, rank_part);
    hipLaunchKernelGGL(k2_prep, dim3(B), dim3(1024), 0, stream, a, y, rank_part, data, out);
    hipLaunchKernelGGL(k3_grad, dim3(B * JC), dim3(1024), 0, stream, data, out);
}

// Round 2
// 95.213 us; speedup vs baseline: 1.0092x; 1.0092x over previous
//
#include <hip/hip_runtime.h>
#include <math.h>

#define N 1024
#define B 32
#define JC 8            // k1 j-chunks per row
#define K1CHUNK 128     // N / JC
#define ICH 64          // i-elements per k2 block
#define NSL 16          // j-slices per i (tid & 15)
#define SIGMA 1.0f
#define FEPS 1.1920928955078125e-07f   // np.finfo(float32).eps
#define LOG2E 1.4426950408889634f

#if defined(__has_builtin) && __has_builtin(__builtin_amdgcn_exp2f)
#define EXP2F(x) __builtin_amdgcn_exp2f(x)
#else
#define EXP2F(x) exp2f(x)
#endif

// K1: partial stable-descending-rank counts over j-chunks; per-row sum(a) -> row_sum.
// grid = B*JC blocks of 256. block bx -> row r = bx>>3, chunk jc = bx&7.
// rank_part layout: [jc][r][i]
__global__ __launch_bounds__(256) void k1_rank(const float* __restrict__ a,
                                               int* __restrict__ rank_part,
                                               float* __restrict__ row_sum) {
    const int bx = blockIdx.x;
    const int r = bx >> 3, jc = bx & 7;
    const int tid = threadIdx.x;

    __shared__ float sA[K1CHUNK];
    if (tid < K1CHUNK) sA[tid] = a[r * N + jc * K1CHUNK + tid];

    float ai[4];
    int ig[4];
#pragma unroll
    for (int k = 0; k < 4; k++) {
        ig[k] = tid + k * 256;
        ai[k] = a[r * N + ig[k]];
    }
    __syncthreads();

    int cnt[4] = {0, 0, 0, 0};
    for (int j = 0; j < K1CHUNK; j++) {
        const float aj = sA[j];
        const int jg = jc * K1CHUNK + j;
#pragma unroll
        for (int k = 0; k < 4; k++) {
            // stable descending rank: count (a_j > a_i) or (tie and j < i)
            cnt[k] += (aj > ai[k]) ? 1 : ((aj == ai[k] && jg < ig[k]) ? 1 : 0);
        }
    }
#pragma unroll
    for (int k = 0; k < 4; k++)
        rank_part[(jc * B + r) * N + ig[k]] = cnt[k];

    if (jc == 0) {  // per-row sum of a for the placeholder loss (no atomics, no zeroing)
        float s = ai[0] + ai[1] + ai[2] + ai[3];
#pragma unroll
        for (int off = 32; off >= 1; off >>= 1) s += __shfl_down(s, off, 64);
        __shared__ float wsum[4];
        if ((tid & 63) == 0) wsum[tid >> 6] = s;
        __syncthreads();
        if (tid == 0) row_sum[r] = wsum[0] + wsum[1] + wsum[2] + wsum[3];
    }
}

// K2: fused prep + pairwise gradient. grid = B*16 blocks of 1024.
// block bx -> row r = bx>>4, i-chunk ic = bx&15 (64 i's).
// Phase A (per element e=tid): rank -> ilr; ballot-histogram idcg; pack
// (2^y * 2sigma/(idcg+eps), ilr, a*log2e) into LDS.
// Phase B: thread (i = ic*64 + tid>>4, slice s = tid&15) loops 64 j's
// (j = jj*16+s: 16 consecutive float4 = 256B contiguous per wave, 2-way bank
// aliasing only). Shfl-reduce over 16 slices -> one direct store per i.
__global__ __launch_bounds__(1024) void k2_fused(const float* __restrict__ a,
                                                 const float* __restrict__ y,
                                                 const int* __restrict__ rank_part,
                                                 const float* __restrict__ row_sum,
                                                 float* __restrict__ out) {
    const int bx = blockIdx.x;
    const int r = bx >> 4, ic = bx & 15;
    const int tid = threadIdx.x;
    const int wid = tid >> 6, lane = tid & 63;

    __shared__ float4 sdat[N];
    __shared__ int hist[16][4];
    __shared__ int tot[4];
    __shared__ float wt[16];
    __shared__ float sC;

    const float ai = a[r * N + tid];
    const float yi = y[r * N + tid];

    int cnt = 0;
#pragma unroll
    for (int jc = 0; jc < JC; jc++) cnt += rank_part[(jc * B + r) * N + tid];
    // pi = cnt+1; ilr = 1/log2(pi+1) = 1/log2(cnt+2)
    const float ilr = __builtin_amdgcn_rcpf(__log2f((float)(cnt + 2)));

    // histogram of y (0..4) via wave ballots (no LDS atomics)
    const unsigned long long b1 = __ballot(yi >= 1.0f);
    const unsigned long long b2 = __ballot(yi >= 2.0f);
    const unsigned long long b3 = __ballot(yi >= 3.0f);
    const unsigned long long b4 = __ballot(yi >= 4.0f);
    if (lane == 0) {
        hist[wid][0] = __popcll(b1);
        hist[wid][1] = __popcll(b2);
        hist[wid][2] = __popcll(b3);
        hist[wid][3] = __popcll(b4);
    }
    __syncthreads();
    if (tid < 4) {
        int t = 0;
#pragma unroll
        for (int w = 0; w < 16; w++) t += hist[w][tid];
        tot[tid] = t;  // tot[v-1] = count(y >= v)
    }
    __syncthreads();
    const int p1 = tot[0], p2 = tot[1], p3 = tot[2], p4 = tot[3];
    // sorted-descending y at position tid, then idcg = sum(gain * discount)
    const int v = (tid < p4) ? 4 : (tid < p3) ? 3 : (tid < p2) ? 2 : (tid < p1) ? 1 : 0;
    float term = (float)((1 << v) - 1) *
                 __builtin_amdgcn_rcpf(__log2f((float)(tid + 2)));
#pragma unroll
    for (int off = 32; off >= 1; off >>= 1) term += __shfl_down(term, off, 64);
    if (lane == 0) wt[wid] = term;
    __syncthreads();
    if (tid == 0) {
        float idcg = 0.f;
#pragma unroll
        for (int w = 0; w < 16; w++) idcg += wt[w];
        sC = 2.0f * SIGMA / (idcg + FEPS);
    }
    if (bx == 0 && wid == 0) {  // loss = sum(a): reduce K1's 32 row sums
        float s = (lane < B) ? row_sum[lane] : 0.f;
#pragma unroll
        for (int off = 16; off >= 1; off >>= 1) s += __shfl_down(s, off, 64);
        if (lane == 0) out[0] = s;
    }
    __syncthreads();
    const float c = sC;
    sdat[tid] = make_float4(EXP2F(yi) * c, ilr, ai * LOG2E, 0.f);
    __syncthreads();

    const int i = ic * ICH + (tid >> 4);
    const int s = tid & 15;
    const float4 di = sdat[i];
    float acc = 0.f;
#pragma unroll 4
    for (int jj = 0; jj < N / NSL; jj++) {
        const float4 dj = sdat[jj * NSL + s];
        const float dg = di.x - dj.x;       // scaled gain diff; sign == sign(y_i-y_j)
        const float dl = di.y - dj.y;       // inv-logrank diff
        const float da = di.z - dj.z;       // (a_i - a_j) * log2(e)
        const float num = dg * fabsf(dl);   // = s_ij * |delta_ndcg| (scale folded)
        const float x = (dg >= 0.f) ? da : -da;
        const float e = EXP2F(x);           // exp(s_ij * (a_i - a_j))
        acc = fmaf(num, __builtin_amdgcn_rcpf(1.0f + e), acc);
    }
#pragma unroll
    for (int off = 8; off >= 1; off >>= 1) acc += __shfl_down(acc, off, 16);
    if (s == 0) out[1 + r * N + i] = -acc;  // exactly one writer per element
}

extern "C" void kernel_launch(void* const* d_in, const int* in_sizes, int n_in,
                              void* d_out, int out_size, void* d_ws, size_t ws_size,
                              hipStream_t stream) {
    (void)in_sizes; (void)n_in; (void)out_size; (void)ws_size;
    const float* a = (const float*)d_in[0];
    const float* y = (const float*)d_in[1];
    float* out = (float*)d_out;

    int* rank_part = (int*)d_ws;                                    // 8*32*1024*4 = 1 MB
    float* row_sum = (float*)((char*)d_ws + (size_t)JC * B * N * sizeof(int)); // 128 B

    hipLaunchKernelGGL(k1_rank, dim3(B * JC), dim3(256), 0, stream, a, rank_part, row_sum);
    hipLaunchKernelGGL(k2_fused, dim3(B * 16), dim3(1024), 0, stream, a, y, rank_part,
                       row_sum, out);
}

// Round 3
// 93.745 us; speedup vs baseline: 1.0250x; 1.0157x over previous
//
#include <hip/hip_runtime.h>
#include <math.h>

#define N 1024
#define B 32
#define JC 8            // k1 j-chunks per row
#define K1CHUNK 128     // N / JC
#define ICH 64          // i-elements per k2 block
#define NSL 16          // j-slices per i (tid & 15)
#define SIGMA 1.0f
#define FEPS 1.1920928955078125e-07f   // np.finfo(float32).eps
#define LOG2E 1.4426950408889634f

#if defined(__has_builtin) && __has_builtin(__builtin_amdgcn_exp2f)
#define EXP2F(x) __builtin_amdgcn_exp2f(x)
#else
#define EXP2F(x) exp2f(x)
#endif

// K1: partial stable-descending-rank counts over j-chunks; per-row sum(a) -> row_sum.
// grid = B*JC blocks of 256. block bx -> row r = bx>>3, chunk jc = bx&7.
// rank_part layout: [jc][r][i]
__global__ __launch_bounds__(256) void k1_rank(const float* __restrict__ a,
                                               int* __restrict__ rank_part,
                                               float* __restrict__ row_sum) {
    const int bx = blockIdx.x;
    const int r = bx >> 3, jc = bx & 7;
    const int tid = threadIdx.x;

    __shared__ float sA[K1CHUNK];
    if (tid < K1CHUNK) sA[tid] = a[r * N + jc * K1CHUNK + tid];

    float ai[4];
    int ig[4];
#pragma unroll
    for (int k = 0; k < 4; k++) {
        ig[k] = tid + k * 256;
        ai[k] = a[r * N + ig[k]];
    }
    __syncthreads();

    int cnt[4] = {0, 0, 0, 0};
    for (int j = 0; j < K1CHUNK; j++) {
        const float aj = sA[j];
        const int jg = jc * K1CHUNK + j;
#pragma unroll
        for (int k = 0; k < 4; k++) {
            // stable descending rank: count (a_j > a_i) or (tie and j < i)
            cnt[k] += (aj > ai[k]) ? 1 : ((aj == ai[k] && jg < ig[k]) ? 1 : 0);
        }
    }
#pragma unroll
    for (int k = 0; k < 4; k++)
        rank_part[(jc * B + r) * N + ig[k]] = cnt[k];

    if (jc == 0) {  // per-row sum of a for the placeholder loss (no atomics, no zeroing)
        float s = ai[0] + ai[1] + ai[2] + ai[3];
#pragma unroll
        for (int off = 32; off >= 1; off >>= 1) s += __shfl_down(s, off, 64);
        __shared__ float wsum[4];
        if ((tid & 63) == 0) wsum[tid >> 6] = s;
        __syncthreads();
        if (tid == 0) row_sum[r] = wsum[0] + wsum[1] + wsum[2] + wsum[3];
    }
}

// K2: fused prep + pairwise gradient. grid = B*16 blocks of 1024.
// block bx -> row r = bx>>4, i-chunk ic = bx&15 (64 i's).
// Phase A (per element e=tid): rank -> ilr; ballot-histogram idcg; pack
// (2^y * 2sigma/(idcg+eps), ilr, e^a) into LDS.
// Phase B: thread (i = ic*64 + tid>>4, slice s = tid&15) loops 64 j's.
// KEY: 1/(1+exp(s*(a_i-a_j))) == (s>0 ? E_j : E_i) / (E_i + E_j) with E=e^a,
// so the inner loop has NO exp — only one rcp transcendental per pair.
// Shfl-reduce over 16 slices -> one direct store per i (no atomics, no zeroing).
__global__ __launch_bounds__(1024) void k2_fused(const float* __restrict__ a,
                                                 const float* __restrict__ y,
                                                 const int* __restrict__ rank_part,
                                                 const float* __restrict__ row_sum,
                                                 float* __restrict__ out) {
    const int bx = blockIdx.x;
    const int r = bx >> 4, ic = bx & 15;
    const int tid = threadIdx.x;
    const int wid = tid >> 6, lane = tid & 63;

    __shared__ float4 sdat[N];
    __shared__ int hist[16][4];
    __shared__ int tot[4];
    __shared__ float wt[16];
    __shared__ float sC;

    const float ai = a[r * N + tid];
    const float yi = y[r * N + tid];

    int cnt = 0;
#pragma unroll
    for (int jc = 0; jc < JC; jc++) cnt += rank_part[(jc * B + r) * N + tid];
    // pi = cnt+1; ilr = 1/log2(pi+1) = 1/log2(cnt+2)
    const float ilr = __builtin_amdgcn_rcpf(__log2f((float)(cnt + 2)));

    // histogram of y (0..4) via wave ballots (no LDS atomics)
    const unsigned long long b1 = __ballot(yi >= 1.0f);
    const unsigned long long b2 = __ballot(yi >= 2.0f);
    const unsigned long long b3 = __ballot(yi >= 3.0f);
    const unsigned long long b4 = __ballot(yi >= 4.0f);
    if (lane == 0) {
        hist[wid][0] = __popcll(b1);
        hist[wid][1] = __popcll(b2);
        hist[wid][2] = __popcll(b3);
        hist[wid][3] = __popcll(b4);
    }
    __syncthreads();
    if (tid < 4) {
        int t = 0;
#pragma unroll
        for (int w = 0; w < 16; w++) t += hist[w][tid];
        tot[tid] = t;  // tot[v-1] = count(y >= v)
    }
    __syncthreads();
    const int p1 = tot[0], p2 = tot[1], p3 = tot[2], p4 = tot[3];
    // sorted-descending y at position tid, then idcg = sum(gain * discount)
    const int v = (tid < p4) ? 4 : (tid < p3) ? 3 : (tid < p2) ? 2 : (tid < p1) ? 1 : 0;
    float term = (float)((1 << v) - 1) *
                 __builtin_amdgcn_rcpf(__log2f((float)(tid + 2)));
#pragma unroll
    for (int off = 32; off >= 1; off >>= 1) term += __shfl_down(term, off, 64);
    if (lane == 0) wt[wid] = term;
    __syncthreads();
    if (tid == 0) {
        float idcg = 0.f;
#pragma unroll
        for (int w = 0; w < 16; w++) idcg += wt[w];
        sC = 2.0f * SIGMA / (idcg + FEPS);
    }
    if (bx == 0 && wid == 0) {  // loss = sum(a): reduce K1's 32 row sums
        float s = (lane < B) ? row_sum[lane] : 0.f;
#pragma unroll
        for (int off = 16; off >= 1; off >>= 1) s += __shfl_down(s, off, 64);
        if (lane == 0) out[0] = s;
    }
    __syncthreads();
    const float c = sC;
    const float Ei = EXP2F(ai * LOG2E);        // e^a_i, computed ONCE per element
    sdat[tid] = make_float4(EXP2F(yi) * c, ilr, Ei, 0.f);
    __syncthreads();

    const int i = ic * ICH + (tid >> 4);
    const int s = tid & 15;
    const float4 di = sdat[i];
    float acc = 0.f;
#pragma unroll 4
    for (int jj = 0; jj < N / NSL; jj++) {
        const float4 dj = sdat[jj * NSL + s];
        const float dg = di.x - dj.x;        // scaled gain diff; sign == sign(y_i-y_j)
        const float dl = di.y - dj.y;        // inv-logrank diff
        const float num = dg * fabsf(dl);    // = s_ij * |delta_ndcg| (scale folded)
        const float sum = di.z + dj.z;       // E_i + E_j
        const float sel = (dg >= 0.f) ? dj.z : di.z;  // sigmoid numerator
        acc = fmaf(num * sel, __builtin_amdgcn_rcpf(sum), acc);
    }
#pragma unroll
    for (int off = 8; off >= 1; off >>= 1) acc += __shfl_down(acc, off, 16);
    if (s == 0) out[1 + r * N + i] = -acc;   // exactly one writer per element
}

extern "C" void kernel_launch(void* const* d_in, const int* in_sizes, int n_in,
                              void* d_out, int out_size, void* d_ws, size_t ws_size,
                              hipStream_t stream) {
    (void)in_sizes; (void)n_in; (void)out_size; (void)ws_size;
    const float* a = (const float*)d_in[0];
    const float* y = (const float*)d_in[1];
    float* out = (float*)d_out;

    int* rank_part = (int*)d_ws;                                    // 8*32*1024*4 = 1 MB
    float* row_sum = (float*)((char*)d_ws + (size_t)JC * B * N * sizeof(int)); // 128 B

    hipLaunchKernelGGL(k1_rank, dim3(B * JC), dim3(256), 0, stream, a, rank_part, row_sum);
    hipLaunchKernelGGL(k2_fused, dim3(B * 16), dim3(1024), 0, stream, a, y, rank_part,
                       row_sum, out);
}